// Round 1
// baseline (2133.100 us; speedup 1.0000x reference)
//
#include <hip/hip_runtime.h>

#define TT 2048
#define HH 64
#define II 6
#define OO 6
#define GG 256
#define NTHR 896

__device__ __forceinline__ float fast_sig(float v) {
    return __builtin_amdgcn_rcpf(1.0f + __expf(-v));
}
__device__ __forceinline__ float fast_tanh(float v) {
    // tanh(v) = 1 - 2/(exp(2v)+1); graceful at +-inf
    return 1.0f - 2.0f * __builtin_amdgcn_rcpf(__expf(2.0f * v) + 1.0f);
}

__global__ __launch_bounds__(NTHR)
void lstm_fused_kernel(const float* __restrict__ x,
                       const float* __restrict__ Wih0, const float* __restrict__ Whh0,
                       const float* __restrict__ b0,
                       const float* __restrict__ Wih1, const float* __restrict__ Whh1,
                       const float* __restrict__ b1,
                       const float* __restrict__ W1, const float* __restrict__ bf1,
                       const float* __restrict__ W2, const float* __restrict__ bf2,
                       float* __restrict__ out)
{
    const int row = blockIdx.x;   // batch row
    const int tid = threadIdx.x;

    __shared__ __attribute__((aligned(16))) float h0buf[2][HH];
    __shared__ __attribute__((aligned(16))) float h1buf[2][HH];
    __shared__ __attribute__((aligned(16))) float rbuf[2][HH];
    __shared__ __attribute__((aligned(16))) float xgbuf[2][GG];
    __shared__ __attribute__((aligned(16))) float gA[GG];
    __shared__ __attribute__((aligned(16))) float gB[GG];

    if (tid < HH) {
        h0buf[0][tid] = 0.f; h0buf[1][tid] = 0.f;
        h1buf[0][tid] = 0.f; h1buf[1][tid] = 0.f;
    }

    // role assignment (wave-aligned boundaries)
    int role, j;
    const float* wptr;
    float bias = 0.f;
    if (tid < 256)      { role = 0; j = tid;       wptr = Whh0 + j * HH; bias = b0[j]; }
    else if (tid < 512) { role = 1; j = tid - 256; wptr = Wih1 + j * HH; bias = b1[j]; }
    else if (tid < 768) { role = 2; j = tid - 512; wptr = Whh1 + j * HH; }
    else if (tid < 832) { role = 3; j = tid - 768; wptr = W1  + j * HH;  bias = bf1[j]; }
    else                { role = 4; j = tid - 832; wptr = W2 + (j < OO ? j : 0) * HH;
                          if (j < OO) bias = bf2[j]; }

    // one 64-float weight row per thread (role-dependent) -> single register array
    float4 w[16];
    #pragma unroll
    for (int q = 0; q < 16; ++q) w[q] = reinterpret_cast<const float4*>(wptr)[q];

    float wx0=0.f,wx1=0.f,wx2=0.f,wx3=0.f,wx4=0.f,wx5=0.f;
    float xc0=0.f,xc1=0.f,xc2=0.f,xc3=0.f,xc4=0.f,xc5=0.f;
    const float* xrow = x + (size_t)row * TT * II;
    if (role == 0) {
        wx0 = Wih0[j*II+0]; wx1 = Wih0[j*II+1]; wx2 = Wih0[j*II+2];
        wx3 = Wih0[j*II+3]; wx4 = Wih0[j*II+4]; wx5 = Wih0[j*II+5];
        xc0 = xrow[0]; xc1 = xrow[1]; xc2 = xrow[2];
        xc3 = xrow[3]; xc4 = xrow[4]; xc5 = xrow[5];
    }

    float* outrow = out + (size_t)row * TT * OO;
    float c = 0.f;   // cell state (phase-2 threads 0-127)

    __syncthreads();

    for (int t = 0; t <= TT + 3; ++t) {
        // ---------------- phase 1 : all dot products ----------------
        if (role == 0) {
            if (t < TT) {
                float acc = bias + wx0*xc0 + wx1*xc1 + wx2*xc2
                                 + wx3*xc3 + wx4*xc4 + wx5*xc5;
                const float4* hp = reinterpret_cast<const float4*>(h0buf[(t-1) & 1]);
                #pragma unroll
                for (int q = 0; q < 16; ++q) {
                    float4 hv = hp[q];
                    acc += w[q].x*hv.x + w[q].y*hv.y + w[q].z*hv.z + w[q].w*hv.w;
                }
                gA[j] = (j < 128 || j >= 192) ? fast_sig(acc) : fast_tanh(acc);
                if (t + 1 < TT) {   // prefetch next x (wave-uniform, L1/L2-hot)
                    const float* xn = xrow + (size_t)(t+1) * II;
                    xc0 = xn[0]; xc1 = xn[1]; xc2 = xn[2];
                    xc3 = xn[3]; xc4 = xn[4]; xc5 = xn[5];
                }
            }
        } else if (role == 1) {
            const int s = t - 1;             // xg1[s] = b1 + Wih1 . h0[s]
            if (s >= 0 && s < TT) {
                float acc = bias;
                const float4* hp = reinterpret_cast<const float4*>(h0buf[s & 1]);
                #pragma unroll
                for (int q = 0; q < 16; ++q) {
                    float4 hv = hp[q];
                    acc += w[q].x*hv.x + w[q].y*hv.y + w[q].z*hv.z + w[q].w*hv.w;
                }
                xgbuf[s & 1][j] = acc;
            }
        } else if (role == 2) {
            const int s = t - 2;             // layer-1 gates at step s
            if (s >= 0 && s < TT) {
                float acc = xgbuf[s & 1][j];
                const float4* hp = reinterpret_cast<const float4*>(h1buf[(s-1) & 1]);
                #pragma unroll
                for (int q = 0; q < 16; ++q) {
                    float4 hv = hp[q];
                    acc += w[q].x*hv.x + w[q].y*hv.y + w[q].z*hv.z + w[q].w*hv.w;
                }
                gB[j] = (j < 128 || j >= 192) ? fast_sig(acc) : fast_tanh(acc);
            }
        } else if (role == 3) {
            const int s = t - 3;             // FC1: relu(W1 . h1[s] + bf1)
            if (s >= 0 && s < TT) {
                float acc = bias;
                const float4* hp = reinterpret_cast<const float4*>(h1buf[s & 1]);
                #pragma unroll
                for (int q = 0; q < 16; ++q) {
                    float4 hv = hp[q];
                    acc += w[q].x*hv.x + w[q].y*hv.y + w[q].z*hv.z + w[q].w*hv.w;
                }
                rbuf[s & 1][j] = fmaxf(acc, 0.f);
            }
        } else {
            const int s = t - 4;             // FC2 -> out[s]
            if (s >= 0 && s < TT && j < OO) {
                float acc = bias;
                const float4* rp = reinterpret_cast<const float4*>(rbuf[s & 1]);
                #pragma unroll
                for (int q = 0; q < 16; ++q) {
                    float4 rv = rp[q];
                    acc += w[q].x*rv.x + w[q].y*rv.y + w[q].z*rv.z + w[q].w*rv.w;
                }
                outrow[(size_t)s * OO + j] = acc;
            }
        }
        __syncthreads();
        // ---------------- phase 2 : cell updates ----------------
        if (tid < 64) {
            if (t < TT) {
                float ig = gA[tid], fg = gA[64+tid], gg = gA[128+tid], og = gA[192+tid];
                c = fg * c + ig * gg;
                h0buf[t & 1][tid] = og * fast_tanh(c);
            }
        } else if (tid < 128) {
            const int s = t - 2;
            if (s >= 0 && s < TT) {
                const int k = tid - 64;
                float ig = gB[k], fg = gB[64+k], gg = gB[128+k], og = gB[192+k];
                c = fg * c + ig * gg;
                h1buf[s & 1][k] = og * fast_tanh(c);
            }
        }
        __syncthreads();
    }
}

extern "C" void kernel_launch(void* const* d_in, const int* in_sizes, int n_in,
                              void* d_out, int out_size, void* d_ws, size_t ws_size,
                              hipStream_t stream) {
    const float* xp   = (const float*)d_in[0];
    const float* Wih0 = (const float*)d_in[1];
    const float* Whh0 = (const float*)d_in[2];
    const float* b0   = (const float*)d_in[3];
    const float* Wih1 = (const float*)d_in[4];
    const float* Whh1 = (const float*)d_in[5];
    const float* b1   = (const float*)d_in[6];
    const float* W1   = (const float*)d_in[7];
    const float* bf1  = (const float*)d_in[8];
    const float* W2   = (const float*)d_in[9];
    const float* bf2  = (const float*)d_in[10];
    float* out = (float*)d_out;

    lstm_fused_kernel<<<dim3(256), dim3(NTHR), 0, stream>>>(
        xp, Wih0, Whh0, b0, Wih1, Whh1, b1, W1, bf1, W2, bf2, out);
}

// Round 2
// 2109.240 us; speedup vs baseline: 1.0113x; 1.0113x over previous
//
#include <hip/hip_runtime.h>

#define TT 2048
#define HH 64
#define II 6
#define OO 6
#define GG 256
#define NTHR 1024   // 16 waves = exactly 4 waves/SIMD -> VGPR cap 128, weights stay resident

__device__ __forceinline__ float fast_sig(float v) {
    return __builtin_amdgcn_rcpf(1.0f + __expf(-v));
}
__device__ __forceinline__ float fast_tanh(float v) {
    // tanh(v) = 1 - 2/(exp(2v)+1); graceful at +-inf
    return 1.0f - 2.0f * __builtin_amdgcn_rcpf(__expf(2.0f * v) + 1.0f);
}

__global__ __launch_bounds__(NTHR, 4)
void lstm_fused_kernel(const float* __restrict__ x,
                       const float* __restrict__ Wih0, const float* __restrict__ Whh0,
                       const float* __restrict__ b0,
                       const float* __restrict__ Wih1, const float* __restrict__ Whh1,
                       const float* __restrict__ b1,
                       const float* __restrict__ W1, const float* __restrict__ bf1,
                       const float* __restrict__ W2, const float* __restrict__ bf2,
                       float* __restrict__ out)
{
    const int row = blockIdx.x;   // batch row
    const int tid = threadIdx.x;

    __shared__ __attribute__((aligned(16))) float h0buf[2][HH];
    __shared__ __attribute__((aligned(16))) float h1buf[2][HH];
    __shared__ __attribute__((aligned(16))) float rbuf[2][HH];
    __shared__ __attribute__((aligned(16))) float xgbuf[2][GG];
    __shared__ __attribute__((aligned(16))) float gA[GG];
    __shared__ __attribute__((aligned(16))) float gB[GG];

    if (tid < HH) {
        h0buf[0][tid] = 0.f; h0buf[1][tid] = 0.f;
        h1buf[0][tid] = 0.f; h1buf[1][tid] = 0.f;
    }

    // role assignment (wave-aligned boundaries)
    int role, j;
    const float* wptr;
    float bias = 0.f;
    if (tid < 256)      { role = 0; j = tid;       wptr = Whh0 + j * HH; bias = b0[j]; }
    else if (tid < 512) { role = 1; j = tid - 256; wptr = Wih1 + j * HH; bias = b1[j]; }
    else if (tid < 768) { role = 2; j = tid - 512; wptr = Whh1 + j * HH; }
    else if (tid < 832) { role = 3; j = tid - 768; wptr = W1  + j * HH;  bias = bf1[j]; }
    else                { role = 4; j = tid - 832; wptr = W2 + (j < OO ? j : 0) * HH;
                          if (j < OO) bias = bf2[j]; }

    // one 64-float weight row per thread (role-dependent) -> 64 resident VGPRs
    float4 w[16];
    #pragma unroll
    for (int q = 0; q < 16; ++q) w[q] = reinterpret_cast<const float4*>(wptr)[q];

    float wx0=0.f,wx1=0.f,wx2=0.f,wx3=0.f,wx4=0.f,wx5=0.f;
    float xc0=0.f,xc1=0.f,xc2=0.f,xc3=0.f,xc4=0.f,xc5=0.f;
    const float* xrow = x + (size_t)row * TT * II;
    if (role == 0) {
        wx0 = Wih0[j*II+0]; wx1 = Wih0[j*II+1]; wx2 = Wih0[j*II+2];
        wx3 = Wih0[j*II+3]; wx4 = Wih0[j*II+4]; wx5 = Wih0[j*II+5];
        xc0 = xrow[0]; xc1 = xrow[1]; xc2 = xrow[2];
        xc3 = xrow[3]; xc4 = xrow[4]; xc5 = xrow[5];
    }

    float* outrow = out + (size_t)row * TT * OO;
    float c = 0.f;   // cell state (phase-2 threads 0-127)

    __syncthreads();

    for (int t = 0; t <= TT + 3; ++t) {
        // ---------------- phase 1 : all dot products ----------------
        if (role == 0) {
            if (t < TT) {
                float acc = bias + wx0*xc0 + wx1*xc1 + wx2*xc2
                                 + wx3*xc3 + wx4*xc4 + wx5*xc5;
                const float4* hp = reinterpret_cast<const float4*>(h0buf[(t-1) & 1]);
                #pragma unroll
                for (int q = 0; q < 16; ++q) {
                    float4 hv = hp[q];
                    acc += w[q].x*hv.x + w[q].y*hv.y + w[q].z*hv.z + w[q].w*hv.w;
                }
                gA[j] = (j < 128 || j >= 192) ? fast_sig(acc) : fast_tanh(acc);
                if (t + 1 < TT) {   // prefetch next x (uniform, L1/L2-hot)
                    const float* xn = xrow + (size_t)(t+1) * II;
                    xc0 = xn[0]; xc1 = xn[1]; xc2 = xn[2];
                    xc3 = xn[3]; xc4 = xn[4]; xc5 = xn[5];
                }
            }
        } else if (role == 1) {
            const int s = t - 1;             // xg1[s] = b1 + Wih1 . h0[s]
            if (s >= 0 && s < TT) {
                float acc = bias;
                const float4* hp = reinterpret_cast<const float4*>(h0buf[s & 1]);
                #pragma unroll
                for (int q = 0; q < 16; ++q) {
                    float4 hv = hp[q];
                    acc += w[q].x*hv.x + w[q].y*hv.y + w[q].z*hv.z + w[q].w*hv.w;
                }
                xgbuf[s & 1][j] = acc;
            }
        } else if (role == 2) {
            const int s = t - 2;             // layer-1 gates at step s
            if (s >= 0 && s < TT) {
                float acc = xgbuf[s & 1][j];
                const float4* hp = reinterpret_cast<const float4*>(h1buf[(s-1) & 1]);
                #pragma unroll
                for (int q = 0; q < 16; ++q) {
                    float4 hv = hp[q];
                    acc += w[q].x*hv.x + w[q].y*hv.y + w[q].z*hv.z + w[q].w*hv.w;
                }
                gB[j] = (j < 128 || j >= 192) ? fast_sig(acc) : fast_tanh(acc);
            }
        } else if (role == 3) {
            const int s = t - 3;             // FC1: relu(W1 . h1[s] + bf1)
            if (s >= 0 && s < TT) {
                float acc = bias;
                const float4* hp = reinterpret_cast<const float4*>(h1buf[s & 1]);
                #pragma unroll
                for (int q = 0; q < 16; ++q) {
                    float4 hv = hp[q];
                    acc += w[q].x*hv.x + w[q].y*hv.y + w[q].z*hv.z + w[q].w*hv.w;
                }
                rbuf[s & 1][j] = fmaxf(acc, 0.f);
            }
        } else {
            const int s = t - 4;             // FC2 -> out[s]
            if (s >= 0 && s < TT && j < OO) {
                float acc = bias;
                const float4* rp = reinterpret_cast<const float4*>(rbuf[s & 1]);
                #pragma unroll
                for (int q = 0; q < 16; ++q) {
                    float4 rv = rp[q];
                    acc += w[q].x*rv.x + w[q].y*rv.y + w[q].z*rv.z + w[q].w*rv.w;
                }
                outrow[(size_t)s * OO + j] = acc;
            }
        }
        __syncthreads();
        // ---------------- phase 2 : cell updates ----------------
        if (tid < 64) {
            if (t < TT) {
                float ig = gA[tid], fg = gA[64+tid], gg = gA[128+tid], og = gA[192+tid];
                c = fg * c + ig * gg;
                h0buf[t & 1][tid] = og * fast_tanh(c);
            }
        } else if (tid < 128) {
            const int s = t - 2;
            if (s >= 0 && s < TT) {
                const int k = tid - 64;
                float ig = gB[k], fg = gB[64+k], gg = gB[128+k], og = gB[192+k];
                c = fg * c + ig * gg;
                h1buf[s & 1][k] = og * fast_tanh(c);
            }
        }
        __syncthreads();
    }
}

extern "C" void kernel_launch(void* const* d_in, const int* in_sizes, int n_in,
                              void* d_out, int out_size, void* d_ws, size_t ws_size,
                              hipStream_t stream) {
    const float* xp   = (const float*)d_in[0];
    const float* Wih0 = (const float*)d_in[1];
    const float* Whh0 = (const float*)d_in[2];
    const float* b0   = (const float*)d_in[3];
    const float* Wih1 = (const float*)d_in[4];
    const float* Whh1 = (const float*)d_in[5];
    const float* b1   = (const float*)d_in[6];
    const float* W1   = (const float*)d_in[7];
    const float* bf1  = (const float*)d_in[8];
    const float* W2   = (const float*)d_in[9];
    const float* bf2  = (const float*)d_in[10];
    float* out = (float*)d_out;

    lstm_fused_kernel<<<dim3(256), dim3(NTHR), 0, stream>>>(
        xp, Wih0, Whh0, b0, Wih1, Whh1, b1, W1, bf1, W2, bf2, out);
}

// Round 3
// 1829.969 us; speedup vs baseline: 1.1656x; 1.1526x over previous
//
#include <hip/hip_runtime.h>

#define TT 2048
#define HH 64
#define II 6
#define OO 6
#define GG 256
#define NTHR 1024   // 16 waves = 4 waves/SIMD, 1 block/CU

__device__ __forceinline__ float fast_sig(float v) {
    return __builtin_amdgcn_rcpf(1.0f + __expf(-v));
}
__device__ __forceinline__ float fast_tanh(float v) {
    // tanh(v) = 1 - 2/(exp(2v)+1); graceful at +-inf
    return 1.0f - 2.0f * __builtin_amdgcn_rcpf(__expf(2.0f * v) + 1.0f);
}

__global__ __launch_bounds__(NTHR)
__attribute__((amdgpu_waves_per_eu(4, 4)))   // pin VGPR budget to 128: no spill-to-scratch
void lstm_fused_kernel(const float* __restrict__ x,
                       const float* __restrict__ Wih0, const float* __restrict__ Whh0,
                       const float* __restrict__ b0,
                       const float* __restrict__ Wih1, const float* __restrict__ Whh1,
                       const float* __restrict__ b1,
                       const float* __restrict__ W1, const float* __restrict__ bf1,
                       const float* __restrict__ W2, const float* __restrict__ bf2,
                       float* __restrict__ out)
{
    const int row = blockIdx.x;   // batch row
    const int tid = threadIdx.x;

    __shared__ __attribute__((aligned(16))) float h0buf[2][HH];
    __shared__ __attribute__((aligned(16))) float h1buf[2][HH];
    __shared__ __attribute__((aligned(16))) float rbuf[2][HH];
    __shared__ __attribute__((aligned(16))) float xgbuf[2][GG];
    __shared__ __attribute__((aligned(16))) float gA[GG];
    __shared__ __attribute__((aligned(16))) float gB[GG];

    if (tid < HH) {
        h0buf[0][tid] = 0.f; h0buf[1][tid] = 0.f;
        h1buf[0][tid] = 0.f; h1buf[1][tid] = 0.f;
    }

    // role assignment (wave-aligned boundaries)
    int role, j;
    const float* wptr;
    float bias = 0.f;
    if (tid < 256)      { role = 0; j = tid;       wptr = Whh0 + j * HH; bias = b0[j]; }
    else if (tid < 512) { role = 1; j = tid - 256; wptr = Wih1 + j * HH; bias = b1[j]; }
    else if (tid < 768) { role = 2; j = tid - 512; wptr = Whh1 + j * HH; }
    else if (tid < 832) { role = 3; j = tid - 768; wptr = W1  + j * HH;  bias = bf1[j]; }
    else                { role = 4; j = tid - 832; wptr = W2 + (j < OO ? j : 0) * HH;
                          if (j < OO) bias = bf2[j]; }

    // one 64-float weight row per thread (role-dependent) -> 64 resident VGPRs
    float4 w[16];
    #pragma unroll
    for (int q = 0; q < 16; ++q) w[q] = reinterpret_cast<const float4*>(wptr)[q];
    // opaque barrier: forbid rematerializing these loads inside the t-loop
    #pragma unroll
    for (int q = 0; q < 16; ++q)
        asm volatile("" : "+v"(w[q].x), "+v"(w[q].y), "+v"(w[q].z), "+v"(w[q].w));

    float wx0=0.f,wx1=0.f,wx2=0.f,wx3=0.f,wx4=0.f,wx5=0.f;
    float xc0=0.f,xc1=0.f,xc2=0.f,xc3=0.f,xc4=0.f,xc5=0.f;
    const float* xrow = x + (size_t)row * TT * II;
    if (role == 0) {
        wx0 = Wih0[j*II+0]; wx1 = Wih0[j*II+1]; wx2 = Wih0[j*II+2];
        wx3 = Wih0[j*II+3]; wx4 = Wih0[j*II+4]; wx5 = Wih0[j*II+5];
        xc0 = xrow[0]; xc1 = xrow[1]; xc2 = xrow[2];
        xc3 = xrow[3]; xc4 = xrow[4]; xc5 = xrow[5];
    }

    float* outrow = out + (size_t)row * TT * OO;
    float c = 0.f;   // cell state (phase-2 threads 0-127)

    __syncthreads();

    for (int t = 0; t <= TT + 3; ++t) {
        // ---------------- phase 1 : all dot products ----------------
        if (role == 0) {
            if (t < TT) {
                float acc = bias + wx0*xc0 + wx1*xc1 + wx2*xc2
                                 + wx3*xc3 + wx4*xc4 + wx5*xc5;
                const float4* hp = reinterpret_cast<const float4*>(h0buf[(t-1) & 1]);
                #pragma unroll
                for (int q = 0; q < 16; ++q) {
                    float4 hv = hp[q];
                    acc += w[q].x*hv.x + w[q].y*hv.y + w[q].z*hv.z + w[q].w*hv.w;
                }
                gA[j] = (j < 128 || j >= 192) ? fast_sig(acc) : fast_tanh(acc);
                if (t + 1 < TT) {   // prefetch next x (uniform, L1/L2-hot)
                    const float* xn = xrow + (size_t)(t+1) * II;
                    xc0 = xn[0]; xc1 = xn[1]; xc2 = xn[2];
                    xc3 = xn[3]; xc4 = xn[4]; xc5 = xn[5];
                }
            }
        } else if (role == 1) {
            const int s = t - 1;             // xg1[s] = b1 + Wih1 . h0[s]
            if (s >= 0 && s < TT) {
                float acc = bias;
                const float4* hp = reinterpret_cast<const float4*>(h0buf[s & 1]);
                #pragma unroll
                for (int q = 0; q < 16; ++q) {
                    float4 hv = hp[q];
                    acc += w[q].x*hv.x + w[q].y*hv.y + w[q].z*hv.z + w[q].w*hv.w;
                }
                xgbuf[s & 1][j] = acc;
            }
        } else if (role == 2) {
            const int s = t - 2;             // layer-1 gates at step s
            if (s >= 0 && s < TT) {
                float acc = xgbuf[s & 1][j];
                const float4* hp = reinterpret_cast<const float4*>(h1buf[(s-1) & 1]);
                #pragma unroll
                for (int q = 0; q < 16; ++q) {
                    float4 hv = hp[q];
                    acc += w[q].x*hv.x + w[q].y*hv.y + w[q].z*hv.z + w[q].w*hv.w;
                }
                gB[j] = (j < 128 || j >= 192) ? fast_sig(acc) : fast_tanh(acc);
            }
        } else if (role == 3) {
            const int s = t - 3;             // FC1: relu(W1 . h1[s] + bf1)
            if (s >= 0 && s < TT) {
                float acc = bias;
                const float4* hp = reinterpret_cast<const float4*>(h1buf[s & 1]);
                #pragma unroll
                for (int q = 0; q < 16; ++q) {
                    float4 hv = hp[q];
                    acc += w[q].x*hv.x + w[q].y*hv.y + w[q].z*hv.z + w[q].w*hv.w;
                }
                rbuf[s & 1][j] = fmaxf(acc, 0.f);
            }
        } else {
            const int s = t - 4;             // FC2 -> out[s]
            if (s >= 0 && s < TT && j < OO) {
                float acc = bias;
                const float4* rp = reinterpret_cast<const float4*>(rbuf[s & 1]);
                #pragma unroll
                for (int q = 0; q < 16; ++q) {
                    float4 rv = rp[q];
                    acc += w[q].x*rv.x + w[q].y*rv.y + w[q].z*rv.z + w[q].w*rv.w;
                }
                outrow[(size_t)s * OO + j] = acc;
            }
        }
        __syncthreads();
        // ---------------- phase 2 : cell updates ----------------
        if (tid < 64) {
            if (t < TT) {
                float ig = gA[tid], fg = gA[64+tid], gg = gA[128+tid], og = gA[192+tid];
                c = fg * c + ig * gg;
                h0buf[t & 1][tid] = og * fast_tanh(c);
            }
        } else if (tid < 128) {
            const int s = t - 2;
            if (s >= 0 && s < TT) {
                const int k = tid - 64;
                float ig = gB[k], fg = gB[64+k], gg = gB[128+k], og = gB[192+k];
                c = fg * c + ig * gg;
                h1buf[s & 1][k] = og * fast_tanh(c);
            }
        }
        __syncthreads();
    }
}

extern "C" void kernel_launch(void* const* d_in, const int* in_sizes, int n_in,
                              void* d_out, int out_size, void* d_ws, size_t ws_size,
                              hipStream_t stream) {
    const float* xp   = (const float*)d_in[0];
    const float* Wih0 = (const float*)d_in[1];
    const float* Whh0 = (const float*)d_in[2];
    const float* b0   = (const float*)d_in[3];
    const float* Wih1 = (const float*)d_in[4];
    const float* Whh1 = (const float*)d_in[5];
    const float* b1   = (const float*)d_in[6];
    const float* W1   = (const float*)d_in[7];
    const float* bf1  = (const float*)d_in[8];
    const float* W2   = (const float*)d_in[9];
    const float* bf2  = (const float*)d_in[10];
    float* out = (float*)d_out;

    lstm_fused_kernel<<<dim3(256), dim3(NTHR), 0, stream>>>(
        xp, Wih0, Whh0, b0, Wih1, Whh1, b1, W1, bf1, W2, bf2, out);
}